// Round 19
// baseline (407.197 us; speedup 1.0000x reference)
//
#include <hip/hip_runtime.h>

typedef unsigned short ushort_t;
typedef unsigned int uint_t;
typedef __attribute__((ext_vector_type(8))) short short8;
typedef __attribute__((ext_vector_type(4))) float f32x4;

#define NN 500000
#define NE 1500000
#define BATCH 64
#define LSEQ 512
#define NSEG (BATCH * LSEQ)          // 32768
#define NBLK_E ((NN + 1023) / 1024)  // 489
#define NBLK_S (NSEG / 1024)         // 32
#define SEQROW 514                   // 512 + 2 zero pad rows
#define WPKN (3 * 4 * 4 * 512)       // 24576 packed conv-weight bf16
#define PSMASK 0x7FFFFu              // 19 bits (NN=500000 < 2^19)
#define NBIN 977                     // ceil(NN/512) bins of 512 i-space nodes
#define CHK 2048                     // edges per chunk
#define NCHK ((NE + CHK - 1) / CHK)  // 733

__device__ inline float bf2f(ushort_t u) {
    union { uint_t u; float f; } c; c.u = ((uint_t)u) << 16; return c.f;
}
__device__ inline ushort_t f2bf(float f) {
    union { float f; uint_t u; } c; c.f = f;
    uint_t u = c.u;
    return (ushort_t)((u + 0x7fff + ((u >> 16) & 1)) >> 16);  // RNE
}
__device__ inline int imax(int a, int b) { return a > b ? a : b; }
__device__ inline int imin(int a, int b) { return a < b ? a : b; }

// ---------------- zero a 4B-word region ----------------
__global__ void k_zero(float* __restrict__ p, int n) {
    int i = blockIdx.x * blockDim.x + threadIdx.x;
    int stride = gridDim.x * blockDim.x;
    for (; i < n; i += stride) p[i] = 0.0f;
}

// ---------------- fused: dst degree histogram (natural) + node seg id/histogram ----------
__global__ void k_hist2(const int* __restrict__ dst, const int* __restrict__ batch,
                        const int* __restrict__ depth, int* __restrict__ cnt,
                        int* __restrict__ segn, int* __restrict__ cnt2) {
    int t = blockIdx.x * blockDim.x + threadIdx.x;
    if (t < NE) {
        atomicAdd(&cnt[dst[t]], 1);
        if (t < NN) {
            int s = batch[t] * LSEQ + depth[t];
            segn[t] = s;
            atomicAdd(&cnt2[s], 1);
        }
    }
}

// ---------------- generic scan (3 kernels) ----------------
__global__ __launch_bounds__(256) void k_scan_block(const int* __restrict__ cnt,
                                                    int* __restrict__ bsum, int n) {
    __shared__ int sd[256];
    int blk = blockIdx.x, tid = threadIdx.x;
    int base = blk * 1024 + tid * 4;
    int s = 0;
#pragma unroll
    for (int k = 0; k < 4; ++k) { int i = base + k; if (i < n) s += cnt[i]; }
    sd[tid] = s;
    __syncthreads();
    for (int off = 128; off; off >>= 1) {
        if (tid < off) sd[tid] += sd[tid + off];
        __syncthreads();
    }
    if (tid == 0) bsum[blk] = sd[0];
}

__global__ __launch_bounds__(512) void k_scan_top(int* __restrict__ bsum, int nblk) {
    __shared__ int sd[512];
    int tid = threadIdx.x;
    int v = (tid < nblk) ? bsum[tid] : 0;
    sd[tid] = v;
    __syncthreads();
    for (int off = 1; off < 512; off <<= 1) {
        int t = (tid >= off) ? sd[tid - off] : 0;
        __syncthreads();
        sd[tid] += t;
        __syncthreads();
    }
    if (tid < nblk) bsum[tid] = sd[tid] - v;  // exclusive
}

__global__ __launch_bounds__(256) void k_scan_final(const int* __restrict__ cnt, const int* __restrict__ bsum,
                                                    int* __restrict__ rowoff, int* __restrict__ cursor,
                                                    int n, int total) {
    __shared__ int sd[256];
    int blk = blockIdx.x, tid = threadIdx.x;
    int base = blk * 1024 + tid * 4;
    int loc[4]; int s = 0;
#pragma unroll
    for (int k = 0; k < 4; ++k) { int i = base + k; int c = (i < n) ? cnt[i] : 0; loc[k] = s; s += c; }
    sd[tid] = s;
    __syncthreads();
    for (int off = 1; off < 256; off <<= 1) {
        int t = (tid >= off) ? sd[tid - off] : 0;
        __syncthreads();
        sd[tid] += t;
        __syncthreads();
    }
    int texc = sd[tid] - s + bsum[blk];
#pragma unroll
    for (int k = 0; k < 4; ++k) {
        int i = base + k;
        if (i < n) { int v = texc + loc[k]; rowoff[i] = v; cursor[i] = v; }
    }
    if (blk == 0 && tid == 0) rowoff[n] = total;
}

// ------- node reorder: nord (seg-sorted -> natural) and pos (natural -> seg-sorted) -------
__global__ void k_nreorder(const int* __restrict__ segn, int* __restrict__ cursor2,
                           int* __restrict__ nord, int* __restrict__ pos) {
    int n = blockIdx.x * blockDim.x + threadIdx.x;
    if (n >= NN) return;
    int p = atomicAdd(&cursor2[segn[n]], 1);
    nord[p] = n;
    pos[n] = p;
}

// ------- prep: i-space degree/dinvs; xs = dinvs*x (src-scaled rows); W2 bf16; conv pack ---
__global__ void k_prep(const int* __restrict__ cnt, const int* __restrict__ nord,
                       float* __restrict__ dinvs, int* __restrict__ cntp,
                       const float* __restrict__ x, float2* __restrict__ xs,
                       const float* __restrict__ W2, ushort_t* __restrict__ W2b,
                       const float* __restrict__ cw, ushort_t* __restrict__ wpk) {
    int i = blockIdx.x * blockDim.x + threadIdx.x;
    if (i < NN) {
        int nd = nord[i];
        int dg = cnt[nd];
        cntp[i] = dg;
        float dv = rsqrtf((float)dg + 1.0f);
        dinvs[i] = dv;
        const float2* x2 = (const float2*)x;
        float2 xv = x2[nd];
        xs[i] = make_float2(dv * xv.x, dv * xv.y);
    }
    if (i < 64 * 64) W2b[i] = f2bf(W2[i]);
    if (i < WPKN) {
        int bq = i & 7, ln = (i >> 3) & 63, ct = (i >> 9) & 3, kk = (i >> 11) & 3, tap = i >> 13;
        int c = ct * 16 + (ln & 15);
        int ii = kk * 32 + (ln >> 4) * 8 + bq;
        wpk[i] = f2bf(cw[c * 384 + ii * 3 + tap]);
    }
}

// ------- binned reorder phase 1: per-chunk LDS histogram -> histg[c][b] -------
__global__ __launch_bounds__(256) void k_binh2(const int* __restrict__ dst,
                                               const int* __restrict__ pos,
                                               int* __restrict__ histg) {
    __shared__ int hist[NBIN];
    int c = blockIdx.x;
    for (int i = threadIdx.x; i < NBIN; i += 256) hist[i] = 0;
    __syncthreads();
    int e0 = c * CHK;
    for (int k = threadIdx.x; k < CHK; k += 256) {
        int e = e0 + k;
        if (e < NE) atomicAdd(&hist[pos[dst[e]] >> 9], 1);
    }
    __syncthreads();
    for (int i = threadIdx.x; i < NBIN; i += 256) histg[c * NBIN + i] = hist[i];
}

// ------- phase 2: per-bin exclusive scan over chunks; base = rowoff[bin*512] -------
// lane-per-bin: coalesced 4B reads across consecutive bins within each chunk row.
__global__ __launch_bounds__(256) void k_binscan(int* __restrict__ histg,
                                                 const int* __restrict__ rowoff) {
    int b = blockIdx.x * 256 + threadIdx.x;
    if (b >= NBIN) return;
    int running = rowoff[b << 9];          // bin base == CSR bin extent start
    for (int c = 0; c < NCHK; ++c) {
        int t = histg[c * NBIN + b];
        histg[c * NBIN + b] = running;     // in-place: becomes per-(chunk,bin) base
        running += t;
    }
}

// ------- phase 3: chunk scatter into bin streams (deterministic bases, LDS cursors) -------
// record: ps(19b) | relpd(9b)<<19
__global__ __launch_bounds__(256) void k_scatA2(const int* __restrict__ src,
                                                const int* __restrict__ dst,
                                                const int* __restrict__ pos,
                                                const int* __restrict__ histg,
                                                uint_t* __restrict__ ebin) {
    __shared__ int cur[NBIN];
    int c = blockIdx.x;
    for (int i = threadIdx.x; i < NBIN; i += 256) cur[i] = histg[c * NBIN + i];
    __syncthreads();
    int e0 = c * CHK;
    for (int k = threadIdx.x; k < CHK; k += 256) {
        int e = e0 + k;
        if (e < NE) {
            int ps = pos[src[e]], pd = pos[dst[e]];
            int q = atomicAdd(&cur[pd >> 9], 1);           // LDS atomic (block-local)
            ebin[q] = (uint_t)ps | ((uint_t)(pd & 511) << 19);
        }
    }
}

// ------- phase 4: per-bin scatter into final CSR slots (L2-local ~6KB windows) -------
__global__ __launch_bounds__(256) void k_scatB(const uint_t* __restrict__ ebin,
                                               const int* __restrict__ rowoff,
                                               int* __restrict__ cursor,
                                               uint_t* __restrict__ epr) {
    int b = blockIdx.x;                 // NBIN bins
    int e0 = rowoff[b << 9];
    int e1 = rowoff[imin((b + 1) << 9, NN)];
    int base = b << 9;
    for (int i = e0 + threadIdx.x; i < e1; i += 256) {
        uint_t r = ebin[i];
        int relpd = (int)((r >> 19) & 511);
        int pd = base + relpd;
        int q = atomicAdd(&cursor[pd], 1);      // 500K cursors: low contention
        epr[q] = (r & PSMASK) | ((uint_t)(relpd & 15) << 19);
    }
}

// ------- FUSED layer-1 + layer-2 GEMM: wave per 16-tile ------
__global__ __launch_bounds__(256) void k_build12(const float2* __restrict__ xs,
                                                 const float* __restrict__ W1,
                                                 const float* __restrict__ b1,
                                                 const float* __restrict__ dinvs,
                                                 const int* __restrict__ rowoff,
                                                 const uint_t* __restrict__ epr,
                                                 const ushort_t* __restrict__ W2b,
                                                 ushort_t* __restrict__ xw2) {
    __shared__ float accs[4][32];        // per-wave: 16 nodes x 2 comps
    __shared__ ushort_t hl[4][16][64];   // per-wave h1 tile (k-swizzled rows)
    int lane = threadIdx.x & 63;
    int wid = threadIdx.x >> 6;
    int wave = (blockIdx.x * blockDim.x + threadIdx.x) >> 6;
    int nwaves = (gridDim.x * blockDim.x) >> 6;
    int col = lane & 15, kg = lane >> 4;
    float w0 = W1[lane], w1 = W1[64 + lane], bj = b1[lane];
    float* a = accs[wid];
    ushort_t (*h)[64] = hl[wid];
    const float* xsf = (const float*)xs;

    short8 bfrag[2][4];
#pragma unroll
    for (int t = 0; t < 2; ++t)
#pragma unroll
        for (int j = 0; j < 4; ++j)
#pragma unroll
            for (int b = 0; b < 8; ++b) {
                int k = t * 32 + kg * 8 + b;
                bfrag[t][j][b] = (short)W2b[k * 64 + j * 16 + col];
            }

    int kblk = lane >> 3, kin = lane & 7;   // channel -> (block, within)
    const int NT = NN / 16;  // 31250
    for (int t = wave; t < NT; t += nwaves) {
        int i0 = t * 16;
        if (lane < 32) a[lane] = xsf[i0 * 2 + lane];   // self terms
        asm volatile("s_waitcnt lgkmcnt(0)" ::: "memory");
        int e1 = rowoff[i0 + 16];
        for (int e = rowoff[i0] + lane; e < e1; e += 64) {   // one edge per lane
            uint_t pr = epr[e];
            float2 xv = xs[pr & PSMASK];
            int loc = (pr >> 19) & 15;
            atomicAdd(&a[loc * 2],     xv.x);
            atomicAdd(&a[loc * 2 + 1], xv.y);
        }
        asm volatile("s_waitcnt lgkmcnt(0)" ::: "memory");
        // h1 rows -> LDS (k-block swizzled: block' = block ^ (j&7))
#pragma unroll
        for (int j = 0; j < 16; ++j) {
            float dv = dinvs[i0 + j];
            float hv = fmaxf((dv * a[j * 2]) * w0 + (dv * a[j * 2 + 1]) * w1 + bj, 0.0f);
            h[j][((kblk ^ (j & 7)) << 3) + kin] = f2bf(hv);
        }
        asm volatile("s_waitcnt lgkmcnt(0)" ::: "memory");
        // A-frags: node=col, k-blocks kg (t0) and kg+4 (t1), un-swizzle with col&7
        short8 a0 = *(const short8*)&h[col][((kg ^ (col & 7)) << 3)];
        short8 a1 = *(const short8*)&h[col][(((kg + 4) ^ (col & 7)) << 3)];
        float dvr[4];
#pragma unroll
        for (int r = 0; r < 4; ++r) dvr[r] = dinvs[i0 + kg * 4 + r];
        size_t base = (size_t)i0 * 64;
        f32x4 acc[4];
#pragma unroll
        for (int j = 0; j < 4; ++j) {
            acc[j] = (f32x4){0.0f, 0.0f, 0.0f, 0.0f};
            acc[j] = __builtin_amdgcn_mfma_f32_16x16x32_bf16(a0, bfrag[0][j], acc[j], 0, 0, 0);
            acc[j] = __builtin_amdgcn_mfma_f32_16x16x32_bf16(a1, bfrag[1][j], acc[j], 0, 0, 0);
        }
#pragma unroll
        for (int j = 0; j < 4; ++j)
#pragma unroll
            for (int r = 0; r < 4; ++r)
                xw2[base + (size_t)(kg * 4 + r) * 64 + j * 16 + col] = f2bf(acc[j][r] * dvr[r]);
    }
}

// ------- layer-2 aggregate: wave per 16-tile, flat edge loop, pure adds in LDS ------
__global__ __launch_bounds__(256) void k_agg3(const ushort_t* __restrict__ xw2s,
                                              const float* __restrict__ b2,
                                              const float* __restrict__ dinvs,
                                              const int* __restrict__ rowoff,
                                              const uint_t* __restrict__ epr,
                                              ushort_t* __restrict__ aggs) {
    __shared__ float accs[4][16][64];   // per-wave tile accumulator (16 KB/block)
    int lane = threadIdx.x & 63;
    int wid = threadIdx.x >> 6;
    int wave = (blockIdx.x * blockDim.x + threadIdx.x) >> 6;
    int nwaves = (gridDim.x * blockDim.x) >> 6;
    float bj = b2[lane];
    float (*a)[64] = accs[wid];
    const int NT = NN / 16;  // 31250
    for (int t = wave; t < NT; t += nwaves) {
        int i0 = t * 16;
#pragma unroll
        for (int j = 0; j < 16; ++j)
            a[j][lane] = bf2f(xw2s[(size_t)(i0 + j) * 64 + lane]);   // sequential
        int e = rowoff[i0], e1 = rowoff[i0 + 16];
        for (; e + 8 <= e1; e += 8) {
            uint_t p[8];
#pragma unroll
            for (int jj = 0; jj < 8; ++jj) p[jj] = epr[e + jj];      // sequential 4B
            float v[8];
#pragma unroll
            for (int jj = 0; jj < 8; ++jj)
                v[jj] = bf2f(xw2s[(size_t)(p[jj] & PSMASK) * 64 + lane]);  // random gather
#pragma unroll
            for (int jj = 0; jj < 8; ++jj)
                a[(p[jj] >> 19) & 15][lane] += v[jj];                 // LDS RMW, pure add
        }
        for (; e < e1; ++e) {
            uint_t p = epr[e];
            a[(p >> 19) & 15][lane] += bf2f(xw2s[(size_t)(p & PSMASK) * 64 + lane]);
        }
#pragma unroll
        for (int j = 0; j < 16; ++j) {
            float dv = dinvs[i0 + j];
            aggs[(size_t)(i0 + j) * 64 + lane] = f2bf(fmaxf(dv * a[j][lane] + bj, 0.0f));
        }
    }
}

// ------- pool: wave per seg, sequential reads; emits bf16 padded seq [b][514][128] -------
__global__ __launch_bounds__(256) void k_pool2(const ushort_t* __restrict__ aggs,
                                               const int* __restrict__ soff,
                                               ushort_t* __restrict__ seqb) {
    int lane = threadIdx.x & 63;
    int seg = (blockIdx.x * blockDim.x + threadIdx.x) >> 6;
    if (seg >= NSEG) return;
    int i0 = soff[seg], i1 = soff[seg + 1];
    float ss = 0.0f, sm = 0.0f;
    for (int i = i0; i < i1; ++i) {
        float v = bf2f(aggs[(size_t)i * 64 + lane]);
        ss += v;
        sm = fmaxf(sm, v);
    }
    float mean = ss / fmaxf((float)(i1 - i0), 1.0f);   // empty seg -> 0/1 = 0
    size_t row = (size_t)(seg >> 9) * SEQROW + 1 + (seg & 511);
    seqb[row * 128 + lane] = f2bf(mean);
    seqb[row * 128 + 64 + lane] = f2bf(sm);            // empty seg max = 0 matches ref
}

// ------- conv1d(k=3,pad=1)+bias+relu+sum over L via MFMA; atomics into pooled -------
__global__ __launch_bounds__(256) void k_convm(const ushort_t* __restrict__ seqb,
                                               const ushort_t* __restrict__ wpk,
                                               const float* __restrict__ cb,
                                               float* __restrict__ pooled) {
    int lane = threadIdx.x & 63;
    int gw = (blockIdx.x * blockDim.x + threadIdx.x) >> 6;   // 0..1023
    int b = gw >> 4;
    int l0base = (gw & 15) * 32;
    int col = lane & 15, kg = lane >> 4;
    float cbv[4];
#pragma unroll
    for (int ct = 0; ct < 4; ++ct) cbv[ct] = cb[ct * 16 + col];
    float csum[4] = {0.0f, 0.0f, 0.0f, 0.0f};
#pragma unroll
    for (int lt = 0; lt < 2; ++lt) {
        int l0 = l0base + lt * 16;
        f32x4 acc[4];
#pragma unroll
        for (int ct = 0; ct < 4; ++ct) acc[ct] = (f32x4){0.0f, 0.0f, 0.0f, 0.0f};
#pragma unroll
        for (int tap = 0; tap < 3; ++tap) {
            size_t row = (size_t)b * SEQROW + l0 + col + tap;  // padded: l_in = l + tap - 1
#pragma unroll
            for (int kk = 0; kk < 4; ++kk) {
                short8 av = *(const short8*)(seqb + row * 128 + kk * 32 + kg * 8);
#pragma unroll
                for (int ct = 0; ct < 4; ++ct) {
                    short8 bv = *(const short8*)(wpk + (((tap * 4 + kk) * 4 + ct) << 9) + lane * 8);
                    acc[ct] = __builtin_amdgcn_mfma_f32_16x16x32_bf16(av, bv, acc[ct], 0, 0, 0);
                }
            }
        }
#pragma unroll
        for (int ct = 0; ct < 4; ++ct)
#pragma unroll
            for (int r = 0; r < 4; ++r)
                csum[ct] += fmaxf(acc[ct][r] + cbv[ct], 0.0f);
    }
#pragma unroll
    for (int ct = 0; ct < 4; ++ct) {
        float v = csum[ct];
        v += __shfl_xor(v, 16, 64);
        v += __shfl_xor(v, 32, 64);
        if (lane < 16) atomicAdd(&pooled[b * 64 + ct * 16 + lane], v);
    }
}

// ---------------- head ----------------
__global__ void k_head(const float* __restrict__ pooled, const float* __restrict__ f1w,
                       const float* __restrict__ f1b, const float* __restrict__ f2w,
                       const float* __restrict__ f2b, float* __restrict__ out) {
    int b = blockIdx.x;
    int j = threadIdx.x;
    const float invL = 1.0f / (float)LSEQ;
    float z = f1b[j];
    for (int c = 0; c < 64; ++c)
        z += (pooled[b * 64 + c] * invL) * f1w[c * 64 + j];
    z = fmaxf(z, 0.0f);
    float v = z * f2w[j];
#pragma unroll
    for (int off = 32; off; off >>= 1) v += __shfl_xor(v, off, 64);
    if (j == 0) out[b] = 1.0f / (1.0f + expf(-(v + f2b[0])));
}

extern "C" void kernel_launch(void* const* d_in, const int* in_sizes, int n_in,
                              void* d_out, int out_size, void* d_ws, size_t ws_size,
                              hipStream_t stream) {
    const float* x     = (const float*)d_in[0];
    const int*   ei    = (const int*)d_in[1];
    const int*   depth = (const int*)d_in[2];
    const int*   batch = (const int*)d_in[3];
    const float* W1    = (const float*)d_in[4];
    const float* b1    = (const float*)d_in[5];
    const float* W2    = (const float*)d_in[6];
    const float* b2    = (const float*)d_in[7];
    const float* cw    = (const float*)d_in[8];
    const float* cb    = (const float*)d_in[9];
    const float* f1w   = (const float*)d_in[10];
    const float* f1b   = (const float*)d_in[11];
    const float* f2w   = (const float*)d_in[12];
    const float* f2b   = (const float*)d_in[13];
    float* out = (float*)d_out;

    // ---- workspace layout (~165 MB), each chunk 16B-aligned ----
    char* p = (char*)d_ws;
    auto bump = [&p](size_t bytes) { char* r = p; p += (bytes + 15) & ~(size_t)15; return r; };
    int*      cnt    = (int*)bump((size_t)NN * 4);             // zeroed ┐
    int*      cnt2   = (int*)bump((size_t)NSEG * 4);           //        │ one
    float*    pool   = (float*)bump((size_t)BATCH * 64 * 4);   //        │ k_zero
    ushort_t* seqb   = (ushort_t*)bump((size_t)BATCH * SEQROW * 128 * 2); // ┘ (pad rows 0)
    int*      segn   = (int*)bump((size_t)NN * 4);
    int*      nord   = (int*)bump((size_t)NN * 4);
    int*      pos    = (int*)bump((size_t)NN * 4);
    int*      soff   = (int*)bump((size_t)(NSEG + 8) * 4);
    int*      cursor2= (int*)bump((size_t)NSEG * 4);
    float*    dinvs  = (float*)bump((size_t)NN * 4);
    float2*   xs     = (float2*)bump((size_t)NN * 8);
    int*      cntp   = (int*)bump((size_t)NN * 4);
    int*      rowoff = (int*)bump((size_t)(NN + 8) * 4);
    int*      cursor = (int*)bump((size_t)NN * 4);
    uint_t*   epr    = (uint_t*)bump((size_t)NE * 4);
    uint_t*   ebin   = (uint_t*)bump((size_t)NE * 4);
    int*      histg  = (int*)bump((size_t)NCHK * NBIN * 4);   // 2.9 MB
    ushort_t* aggs   = (ushort_t*)bump((size_t)NN * 128);
    ushort_t* xw2s   = (ushort_t*)bump((size_t)NN * 128);
    ushort_t* W2b    = (ushort_t*)bump((size_t)64 * 64 * 2);
    ushort_t* wpk    = (ushort_t*)bump((size_t)WPKN * 2);
    int*      bsum   = (int*)bump((size_t)512 * 4);
    int*      bsum2  = (int*)bump((size_t)64 * 4);

    const int* src = ei;
    const int* dst = ei + NE;

    // zero: cnt + cnt2 + pool + seqb (contiguous by layout)
    int zn = NN + NSEG + BATCH * 64 + BATCH * SEQROW * 64 + 16;
    k_zero<<<2048, 256, 0, stream>>>((float*)cnt, zn);

    // degree (natural) + seg histograms
    k_hist2<<<(NE + 255) / 256, 256, 0, stream>>>(dst, batch, depth, cnt, segn, cnt2);

    // seg scan -> soff/cursor2 ; node reorder -> nord/pos
    k_scan_block<<<NBLK_S, 256, 0, stream>>>(cnt2, bsum2, NSEG);
    k_scan_top<<<1, 512, 0, stream>>>(bsum2, NBLK_S);
    k_scan_final<<<NBLK_S, 256, 0, stream>>>(cnt2, bsum2, soff, cursor2, NSEG, NN);
    k_nreorder<<<(NN + 255) / 256, 256, 0, stream>>>(segn, cursor2, nord, pos);

    // i-space degrees/dinvs/xs; W2 bf16; conv-weight frag pack
    k_prep<<<(NN + 255) / 256, 256, 0, stream>>>(cnt, nord, dinvs, cntp, x, xs, W2, W2b, cw, wpk);

    // i-space CSR offsets
    k_scan_block<<<NBLK_E, 256, 0, stream>>>(cntp, bsum, NN);
    k_scan_top<<<1, 512, 0, stream>>>(bsum, NBLK_E);
    k_scan_final<<<NBLK_E, 256, 0, stream>>>(cntp, bsum, rowoff, cursor, NN, NE);

    // deterministic binned reorder: hist -> scan -> bin streams -> CSR
    k_binh2<<<NCHK, 256, 0, stream>>>(dst, pos, histg);
    k_binscan<<<(NBIN + 255) / 256, 256, 0, stream>>>(histg, rowoff);
    k_scatA2<<<NCHK, 256, 0, stream>>>(src, dst, pos, histg, ebin);
    k_scatB<<<NBIN, 256, 0, stream>>>(ebin, rowoff, cursor, epr);

    // fused layer-1 + layer-2 GEMM (writes xw2s directly)
    k_build12<<<4096, 256, 0, stream>>>(xs, W1, b1, dinvs, rowoff, epr, W2b, xw2s);

    // layer-2 aggregate (flat edge loop, pure adds, LDS accumulators)
    k_agg3<<<4096, 256, 0, stream>>>(xw2s, b2, dinvs, rowoff, epr, aggs);

    // pool (sequential over seg-sorted rows) -> bf16 padded seq
    k_pool2<<<NSEG / 4, 256, 0, stream>>>(aggs, soff, seqb);

    // conv + bias + relu + L-sum via MFMA
    k_convm<<<256, 256, 0, stream>>>(seqb, wpk, cb, pool);

    // head
    k_head<<<BATCH, 64, 0, stream>>>(pool, f1w, f1b, f2w, f2b, out);
}

// Round 21
// 292.531 us; speedup vs baseline: 1.3920x; 1.3920x over previous
//
#include <hip/hip_runtime.h>

typedef unsigned short ushort_t;
typedef unsigned int uint_t;
typedef __attribute__((ext_vector_type(8))) short short8;
typedef __attribute__((ext_vector_type(4))) float f32x4;

#define NN 500000
#define NE 1500000
#define BATCH 64
#define LSEQ 512
#define NSEG (BATCH * LSEQ)          // 32768
#define NBLK_S (NSEG / 1024)         // 32
#define SEQROW 514                   // 512 + 2 zero pad rows
#define WPKN (3 * 4 * 4 * 512)       // 24576 packed conv-weight bf16
#define PSMASK 0x7FFFFu              // 19 bits (NN=500000 < 2^19)
#define BSH 12                       // bin shift
#define BSZ 4096                     // nodes per bin
#define NBIN2 ((NN + BSZ - 1) / BSZ) // 123
#define NCHK2 256
#define CHK2 ((NE + NCHK2 - 1) / NCHK2)  // 5860

__device__ inline float bf2f(ushort_t u) {
    union { uint_t u; float f; } c; c.u = ((uint_t)u) << 16; return c.f;
}
__device__ inline ushort_t f2bf(float f) {
    union { float f; uint_t u; } c; c.f = f;
    uint_t u = c.u;
    return (ushort_t)((u + 0x7fff + ((u >> 16) & 1)) >> 16);  // RNE
}
__device__ inline int imin(int a, int b) { return a < b ? a : b; }

// ---------------- zero a 4B-word region ----------------
__global__ void k_zero(float* __restrict__ p, int n) {
    int i = blockIdx.x * blockDim.x + threadIdx.x;
    int stride = gridDim.x * blockDim.x;
    for (; i < n; i += stride) p[i] = 0.0f;
}

// ---------------- node seg id + seg histogram (no degree histogram needed) -------------
__global__ void k_seg(const int* __restrict__ batch, const int* __restrict__ depth,
                      int* __restrict__ segn, int* __restrict__ cnt2) {
    int n = blockIdx.x * blockDim.x + threadIdx.x;
    if (n < NN) {
        int s = batch[n] * LSEQ + depth[n];
        segn[n] = s;
        atomicAdd(&cnt2[s], 1);
    }
}

// ---------------- generic scan (3 kernels), used for seg offsets ----------------
__global__ __launch_bounds__(256) void k_scan_block(const int* __restrict__ cnt,
                                                    int* __restrict__ bsum, int n) {
    __shared__ int sd[256];
    int blk = blockIdx.x, tid = threadIdx.x;
    int base = blk * 1024 + tid * 4;
    int s = 0;
#pragma unroll
    for (int k = 0; k < 4; ++k) { int i = base + k; if (i < n) s += cnt[i]; }
    sd[tid] = s;
    __syncthreads();
    for (int off = 128; off; off >>= 1) {
        if (tid < off) sd[tid] += sd[tid + off];
        __syncthreads();
    }
    if (tid == 0) bsum[blk] = sd[0];
}

__global__ __launch_bounds__(512) void k_scan_top(int* __restrict__ bsum, int nblk) {
    __shared__ int sd[512];
    int tid = threadIdx.x;
    int v = (tid < nblk) ? bsum[tid] : 0;
    sd[tid] = v;
    __syncthreads();
    for (int off = 1; off < 512; off <<= 1) {
        int t = (tid >= off) ? sd[tid - off] : 0;
        __syncthreads();
        sd[tid] += t;
        __syncthreads();
    }
    if (tid < nblk) bsum[tid] = sd[tid] - v;  // exclusive
}

__global__ __launch_bounds__(256) void k_scan_final(const int* __restrict__ cnt, const int* __restrict__ bsum,
                                                    int* __restrict__ rowoff, int* __restrict__ cursor,
                                                    int n, int total) {
    __shared__ int sd[256];
    int blk = blockIdx.x, tid = threadIdx.x;
    int base = blk * 1024 + tid * 4;
    int loc[4]; int s = 0;
#pragma unroll
    for (int k = 0; k < 4; ++k) { int i = base + k; int c = (i < n) ? cnt[i] : 0; loc[k] = s; s += c; }
    sd[tid] = s;
    __syncthreads();
    for (int off = 1; off < 256; off <<= 1) {
        int t = (tid >= off) ? sd[tid - off] : 0;
        __syncthreads();
        sd[tid] += t;
        __syncthreads();
    }
    int texc = sd[tid] - s + bsum[blk];
#pragma unroll
    for (int k = 0; k < 4; ++k) {
        int i = base + k;
        if (i < n) { int v = texc + loc[k]; rowoff[i] = v; cursor[i] = v; }
    }
    if (blk == 0 && tid == 0) rowoff[n] = total;
}

// ------- node reorder: nord (seg-sorted -> natural) and pos (natural -> seg-sorted) -------
__global__ void k_nreorder(const int* __restrict__ segn, int* __restrict__ cursor2,
                           int* __restrict__ nord, int* __restrict__ pos) {
    int n = blockIdx.x * blockDim.x + threadIdx.x;
    if (n >= NN) return;
    int p = atomicAdd(&cursor2[segn[n]], 1);
    nord[p] = n;
    pos[n] = p;
}

// ------- prep weights: W2 bf16; conv-weight frag pack -------
__global__ void k_prepW(const float* __restrict__ W2, ushort_t* __restrict__ W2b,
                        const float* __restrict__ cw, ushort_t* __restrict__ wpk) {
    int i = blockIdx.x * blockDim.x + threadIdx.x;
    if (i < 64 * 64) W2b[i] = f2bf(W2[i]);
    if (i < WPKN) {
        int bq = i & 7, ln = (i >> 3) & 63, ct = (i >> 9) & 3, kk = (i >> 11) & 3, tap = i >> 13;
        int c = ct * 16 + (ln & 15);
        int ii = kk * 32 + (ln >> 4) * 8 + bq;
        wpk[i] = f2bf(cw[c * 384 + ii * 3 + tap]);
    }
}

// ------- prep xs = dinvs * x[nord[i]] (after binsort provides dinvs) -------
__global__ void k_prepx(const float* __restrict__ x, const int* __restrict__ nord,
                        const float* __restrict__ dinvs, float2* __restrict__ xs) {
    int i = blockIdx.x * blockDim.x + threadIdx.x;
    if (i >= NN) return;
    float dv = dinvs[i];
    const float2* x2 = (const float2*)x;
    float2 xv = x2[nord[i]];
    xs[i] = make_float2(dv * xv.x, dv * xv.y);
}

// ------- binned reorder phase 1: per-chunk LDS histogram over 123 bins -------
__global__ __launch_bounds__(256) void k_binh2(const int* __restrict__ dst,
                                               const int* __restrict__ pos,
                                               int* __restrict__ histg) {
    __shared__ int hist[NBIN2];
    int c = blockIdx.x;
    for (int i = threadIdx.x; i < NBIN2; i += 256) hist[i] = 0;
    __syncthreads();
    int e0 = c * CHK2, e1 = imin(e0 + CHK2, NE);
    for (int e = e0 + threadIdx.x; e < e1; e += 256)
        atomicAdd(&hist[pos[dst[e]] >> BSH], 1);
    __syncthreads();
    for (int i = threadIdx.x; i < NBIN2; i += 256) histg[c * NBIN2 + i] = hist[i];
}

// ------- phase 2a: bin totals (wave-parallel column sum) -------
__global__ __launch_bounds__(64) void k_binT(const int* __restrict__ histg, int* __restrict__ T) {
    int b = blockIdx.x, lane = threadIdx.x;
    int s = 0;
    for (int c = lane; c < NCHK2; c += 64) s += histg[c * NBIN2 + b];
#pragma unroll
    for (int off = 32; off; off >>= 1) s += __shfl_down(s, off, 64);
    if (lane == 0) T[b] = s;
}

// ------- phase 2b: bin offsets (single-block scan over 123) -------
__global__ __launch_bounds__(128) void k_boff(const int* __restrict__ T, int* __restrict__ boff) {
    __shared__ int sd[128];
    int t = threadIdx.x;
    int v = (t < NBIN2) ? T[t] : 0;
    sd[t] = v;
    __syncthreads();
    for (int off = 1; off < 128; off <<= 1) {
        int y = (t >= off) ? sd[t - off] : 0;
        __syncthreads();
        sd[t] += y;
        __syncthreads();
    }
    if (t < NBIN2) boff[t] = sd[t] - v;
    if (t == 0) boff[NBIN2] = NE;
}

// ------- phase 2c: per-(chunk,bin) bases in-place (wave scan, 4 chunks/lane) -------
__global__ __launch_bounds__(64) void k_binbase(int* __restrict__ histg, const int* __restrict__ boff) {
    int b = blockIdx.x, lane = threadIdx.x;
    int h[4]; int s = 0;
#pragma unroll
    for (int k = 0; k < 4; ++k) h[k] = histg[(lane * 4 + k) * NBIN2 + b];
#pragma unroll
    for (int k = 0; k < 4; ++k) { int pre = s; s += h[k]; h[k] = pre; }
    int x = s;
    for (int d = 1; d < 64; d <<= 1) { int y = __shfl_up(x, d, 64); if (lane >= d) x += y; }
    int base = x - s + boff[b];
#pragma unroll
    for (int k = 0; k < 4; ++k) histg[(lane * 4 + k) * NBIN2 + b] = base + h[k];
}

// ------- phase 3: chunk scatter to bin streams (LDS cursors, dense line fills) -------
// record: ps(19b) | rel12(12b)<<19
__global__ __launch_bounds__(256) void k_scatA2(const int* __restrict__ src,
                                                const int* __restrict__ dst,
                                                const int* __restrict__ pos,
                                                const int* __restrict__ histg,
                                                uint_t* __restrict__ ebin) {
    __shared__ int cur[NBIN2];
    int c = blockIdx.x;
    for (int i = threadIdx.x; i < NBIN2; i += 256) cur[i] = histg[c * NBIN2 + i];
    __syncthreads();
    int e0 = c * CHK2, e1 = imin(e0 + CHK2, NE);
    for (int e = e0 + threadIdx.x; e < e1; e += 256) {
        int ps = pos[src[e]], pd = pos[dst[e]];
        int q = atomicAdd(&cur[pd >> BSH], 1);
        ebin[q] = (uint_t)ps | ((uint_t)(pd & (BSZ - 1)) << 19);
    }
}

// ------- phase 4: per-bin local sort -> epr + rowoff + dinvs (NO global atomics) -------
__global__ __launch_bounds__(256) void k_binsort(const uint_t* __restrict__ ebin,
                                                 const int* __restrict__ boff,
                                                 uint_t* __restrict__ epr,
                                                 int* __restrict__ rowoff,
                                                 float* __restrict__ dinvs) {
    __shared__ int lh[BSZ];
    __shared__ int sd[256];
    int b = blockIdx.x, tid = threadIdx.x;
    for (int j = tid; j < BSZ; j += 256) lh[j] = 0;
    __syncthreads();
    int e0 = boff[b], e1 = boff[b + 1];
    for (int i = e0 + tid; i < e1; i += 256)
        atomicAdd(&lh[(ebin[i] >> 19) & (BSZ - 1)], 1);
    __syncthreads();
    // block exclusive scan over 4096 (16 per thread)
    int cnt16[16]; int s = 0;
    int base16 = tid * 16;
#pragma unroll
    for (int k = 0; k < 16; ++k) { cnt16[k] = lh[base16 + k]; s += cnt16[k]; }
    sd[tid] = s;
    __syncthreads();
    for (int off = 1; off < 256; off <<= 1) {
        int y = (tid >= off) ? sd[tid - off] : 0;
        __syncthreads();
        sd[tid] += y;
        __syncthreads();
    }
    int run = sd[tid] - s;
    int gbase = b << BSH;
#pragma unroll
    for (int k = 0; k < 16; ++k) {
        int j = base16 + k;
        int g = gbase + j;
        if (g < NN) {
            rowoff[g] = e0 + run;
            dinvs[g] = rsqrtf((float)cnt16[k] + 1.0f);
        }
        lh[j] = run;   // local cursor
        run += cnt16[k];
    }
    if (b == NBIN2 - 1 && tid == 0) rowoff[NN] = NE;
    __syncthreads();
    for (int i = e0 + tid; i < e1; i += 256) {
        uint_t r = ebin[i];
        int rel = (r >> 19) & (BSZ - 1);
        int q = e0 + atomicAdd(&lh[rel], 1);   // LDS atomic
        epr[q] = (r & PSMASK) | ((uint_t)(rel & 15) << 19);
    }
}

// ------- FUSED layer-1 + layer-2 GEMM: wave per 16-tile ------
__global__ __launch_bounds__(256) void k_build12(const float2* __restrict__ xs,
                                                 const float* __restrict__ W1,
                                                 const float* __restrict__ b1,
                                                 const float* __restrict__ dinvs,
                                                 const int* __restrict__ rowoff,
                                                 const uint_t* __restrict__ epr,
                                                 const ushort_t* __restrict__ W2b,
                                                 ushort_t* __restrict__ xw2) {
    __shared__ float accs[4][32];        // per-wave: 16 nodes x 2 comps
    __shared__ ushort_t hl[4][16][64];   // per-wave h1 tile (k-swizzled rows)
    int lane = threadIdx.x & 63;
    int wid = threadIdx.x >> 6;
    int wave = (blockIdx.x * blockDim.x + threadIdx.x) >> 6;
    int nwaves = (gridDim.x * blockDim.x) >> 6;
    int col = lane & 15, kg = lane >> 4;
    float w0 = W1[lane], w1 = W1[64 + lane], bj = b1[lane];
    float* a = accs[wid];
    ushort_t (*h)[64] = hl[wid];
    const float* xsf = (const float*)xs;

    short8 bfrag[2][4];
#pragma unroll
    for (int t = 0; t < 2; ++t)
#pragma unroll
        for (int j = 0; j < 4; ++j)
#pragma unroll
            for (int b = 0; b < 8; ++b) {
                int k = t * 32 + kg * 8 + b;
                bfrag[t][j][b] = (short)W2b[k * 64 + j * 16 + col];
            }

    int kblk = lane >> 3, kin = lane & 7;   // channel -> (block, within)
    const int NT = NN / 16;  // 31250
    for (int t = wave; t < NT; t += nwaves) {
        int i0 = t * 16;
        if (lane < 32) a[lane] = xsf[i0 * 2 + lane];   // self terms
        asm volatile("s_waitcnt lgkmcnt(0)" ::: "memory");
        int e1 = rowoff[i0 + 16];
        for (int e = rowoff[i0] + lane; e < e1; e += 64) {   // one edge per lane
            uint_t pr = epr[e];
            float2 xv = xs[pr & PSMASK];
            int loc = (pr >> 19) & 15;
            atomicAdd(&a[loc * 2],     xv.x);
            atomicAdd(&a[loc * 2 + 1], xv.y);
        }
        asm volatile("s_waitcnt lgkmcnt(0)" ::: "memory");
        // h1 rows -> LDS (k-block swizzled: block' = block ^ (j&7))
#pragma unroll
        for (int j = 0; j < 16; ++j) {
            float dv = dinvs[i0 + j];
            float hv = fmaxf((dv * a[j * 2]) * w0 + (dv * a[j * 2 + 1]) * w1 + bj, 0.0f);
            h[j][((kblk ^ (j & 7)) << 3) + kin] = f2bf(hv);
        }
        asm volatile("s_waitcnt lgkmcnt(0)" ::: "memory");
        short8 a0 = *(const short8*)&h[col][((kg ^ (col & 7)) << 3)];
        short8 a1 = *(const short8*)&h[col][(((kg + 4) ^ (col & 7)) << 3)];
        float dvr[4];
#pragma unroll
        for (int r = 0; r < 4; ++r) dvr[r] = dinvs[i0 + kg * 4 + r];
        size_t base = (size_t)i0 * 64;
        f32x4 acc[4];
#pragma unroll
        for (int j = 0; j < 4; ++j) {
            acc[j] = (f32x4){0.0f, 0.0f, 0.0f, 0.0f};
            acc[j] = __builtin_amdgcn_mfma_f32_16x16x32_bf16(a0, bfrag[0][j], acc[j], 0, 0, 0);
            acc[j] = __builtin_amdgcn_mfma_f32_16x16x32_bf16(a1, bfrag[1][j], acc[j], 0, 0, 0);
        }
#pragma unroll
        for (int j = 0; j < 4; ++j)
#pragma unroll
            for (int r = 0; r < 4; ++r)
                xw2[base + (size_t)(kg * 4 + r) * 64 + j * 16 + col] = f2bf(acc[j][r] * dvr[r]);
    }
}

// ------- layer-2 aggregate: wave per 16-tile, flat edge loop, pure adds in LDS ------
__global__ __launch_bounds__(256) void k_agg3(const ushort_t* __restrict__ xw2s,
                                              const float* __restrict__ b2,
                                              const float* __restrict__ dinvs,
                                              const int* __restrict__ rowoff,
                                              const uint_t* __restrict__ epr,
                                              ushort_t* __restrict__ aggs) {
    __shared__ float accs[4][16][64];   // per-wave tile accumulator (16 KB/block)
    int lane = threadIdx.x & 63;
    int wid = threadIdx.x >> 6;
    int wave = (blockIdx.x * blockDim.x + threadIdx.x) >> 6;
    int nwaves = (gridDim.x * blockDim.x) >> 6;
    float bj = b2[lane];
    float (*a)[64] = accs[wid];
    const int NT = NN / 16;  // 31250
    for (int t = wave; t < NT; t += nwaves) {
        int i0 = t * 16;
#pragma unroll
        for (int j = 0; j < 16; ++j)
            a[j][lane] = bf2f(xw2s[(size_t)(i0 + j) * 64 + lane]);   // sequential
        int e = rowoff[i0], e1 = rowoff[i0 + 16];
        for (; e + 8 <= e1; e += 8) {
            uint_t p[8];
#pragma unroll
            for (int jj = 0; jj < 8; ++jj) p[jj] = epr[e + jj];      // sequential 4B
            float v[8];
#pragma unroll
            for (int jj = 0; jj < 8; ++jj)
                v[jj] = bf2f(xw2s[(size_t)(p[jj] & PSMASK) * 64 + lane]);  // random gather
#pragma unroll
            for (int jj = 0; jj < 8; ++jj)
                a[(p[jj] >> 19) & 15][lane] += v[jj];                 // LDS RMW, pure add
        }
        for (; e < e1; ++e) {
            uint_t p = epr[e];
            a[(p >> 19) & 15][lane] += bf2f(xw2s[(size_t)(p & PSMASK) * 64 + lane]);
        }
#pragma unroll
        for (int j = 0; j < 16; ++j) {
            float dv = dinvs[i0 + j];
            aggs[(size_t)(i0 + j) * 64 + lane] = f2bf(fmaxf(dv * a[j][lane] + bj, 0.0f));
        }
    }
}

// ------- pool: wave per seg, sequential reads; emits bf16 padded seq [b][514][128] -------
__global__ __launch_bounds__(256) void k_pool2(const ushort_t* __restrict__ aggs,
                                               const int* __restrict__ soff,
                                               ushort_t* __restrict__ seqb) {
    int lane = threadIdx.x & 63;
    int seg = (blockIdx.x * blockDim.x + threadIdx.x) >> 6;
    if (seg >= NSEG) return;
    int i0 = soff[seg], i1 = soff[seg + 1];
    float ss = 0.0f, sm = 0.0f;
    for (int i = i0; i < i1; ++i) {
        float v = bf2f(aggs[(size_t)i * 64 + lane]);
        ss += v;
        sm = fmaxf(sm, v);
    }
    float mean = ss / fmaxf((float)(i1 - i0), 1.0f);   // empty seg -> 0/1 = 0
    size_t row = (size_t)(seg >> 9) * SEQROW + 1 + (seg & 511);
    seqb[row * 128 + lane] = f2bf(mean);
    seqb[row * 128 + 64 + lane] = f2bf(sm);            // empty seg max = 0 matches ref
}

// ------- conv1d(k=3,pad=1)+bias+relu+sum over L via MFMA; atomics into pooled -------
__global__ __launch_bounds__(256) void k_convm(const ushort_t* __restrict__ seqb,
                                               const ushort_t* __restrict__ wpk,
                                               const float* __restrict__ cb,
                                               float* __restrict__ pooled) {
    int lane = threadIdx.x & 63;
    int gw = (blockIdx.x * blockDim.x + threadIdx.x) >> 6;   // 0..1023
    int b = gw >> 4;
    int l0base = (gw & 15) * 32;
    int col = lane & 15, kg = lane >> 4;
    float cbv[4];
#pragma unroll
    for (int ct = 0; ct < 4; ++ct) cbv[ct] = cb[ct * 16 + col];
    float csum[4] = {0.0f, 0.0f, 0.0f, 0.0f};
#pragma unroll
    for (int lt = 0; lt < 2; ++lt) {
        int l0 = l0base + lt * 16;
        f32x4 acc[4];
#pragma unroll
        for (int ct = 0; ct < 4; ++ct) acc[ct] = (f32x4){0.0f, 0.0f, 0.0f, 0.0f};
#pragma unroll
        for (int tap = 0; tap < 3; ++tap) {
            size_t row = (size_t)b * SEQROW + l0 + col + tap;  // padded: l_in = l + tap - 1
#pragma unroll
            for (int kk = 0; kk < 4; ++kk) {
                short8 av = *(const short8*)(seqb + row * 128 + kk * 32 + kg * 8);
#pragma unroll
                for (int ct = 0; ct < 4; ++ct) {
                    short8 bv = *(const short8*)(wpk + (((tap * 4 + kk) * 4 + ct) << 9) + lane * 8);
                    acc[ct] = __builtin_amdgcn_mfma_f32_16x16x32_bf16(av, bv, acc[ct], 0, 0, 0);
                }
            }
        }
#pragma unroll
        for (int ct = 0; ct < 4; ++ct)
#pragma unroll
            for (int r = 0; r < 4; ++r)
                csum[ct] += fmaxf(acc[ct][r] + cbv[ct], 0.0f);
    }
#pragma unroll
    for (int ct = 0; ct < 4; ++ct) {
        float v = csum[ct];
        v += __shfl_xor(v, 16, 64);
        v += __shfl_xor(v, 32, 64);
        if (lane < 16) atomicAdd(&pooled[b * 64 + ct * 16 + lane], v);
    }
}

// ---------------- head ----------------
__global__ void k_head(const float* __restrict__ pooled, const float* __restrict__ f1w,
                       const float* __restrict__ f1b, const float* __restrict__ f2w,
                       const float* __restrict__ f2b, float* __restrict__ out) {
    int b = blockIdx.x;
    int j = threadIdx.x;
    const float invL = 1.0f / (float)LSEQ;
    float z = f1b[j];
    for (int c = 0; c < 64; ++c)
        z += (pooled[b * 64 + c] * invL) * f1w[c * 64 + j];
    z = fmaxf(z, 0.0f);
    float v = z * f2w[j];
#pragma unroll
    for (int off = 32; off; off >>= 1) v += __shfl_xor(v, off, 64);
    if (j == 0) out[b] = 1.0f / (1.0f + expf(-(v + f2b[0])));
}

extern "C" void kernel_launch(void* const* d_in, const int* in_sizes, int n_in,
                              void* d_out, int out_size, void* d_ws, size_t ws_size,
                              hipStream_t stream) {
    const float* x     = (const float*)d_in[0];
    const int*   ei    = (const int*)d_in[1];
    const int*   depth = (const int*)d_in[2];
    const int*   batch = (const int*)d_in[3];
    const float* W1    = (const float*)d_in[4];
    const float* b1    = (const float*)d_in[5];
    const float* W2    = (const float*)d_in[6];
    const float* b2    = (const float*)d_in[7];
    const float* cw    = (const float*)d_in[8];
    const float* cb    = (const float*)d_in[9];
    const float* f1w   = (const float*)d_in[10];
    const float* f1b   = (const float*)d_in[11];
    const float* f2w   = (const float*)d_in[12];
    const float* f2b   = (const float*)d_in[13];
    float* out = (float*)d_out;

    // ---- workspace layout (~160 MB), each chunk 16B-aligned ----
    char* p = (char*)d_ws;
    auto bump = [&p](size_t bytes) { char* r = p; p += (bytes + 15) & ~(size_t)15; return r; };
    int*      cnt2   = (int*)bump((size_t)NSEG * 4);           // zeroed ┐
    float*    pool   = (float*)bump((size_t)BATCH * 64 * 4);   //        │ one k_zero
    ushort_t* seqb   = (ushort_t*)bump((size_t)BATCH * SEQROW * 128 * 2); // ┘
    int*      segn   = (int*)bump((size_t)NN * 4);
    int*      nord   = (int*)bump((size_t)NN * 4);
    int*      pos    = (int*)bump((size_t)NN * 4);
    int*      soff   = (int*)bump((size_t)(NSEG + 8) * 4);
    int*      cursor2= (int*)bump((size_t)NSEG * 4);
    float*    dinvs  = (float*)bump((size_t)NN * 4);
    float2*   xs     = (float2*)bump((size_t)NN * 8);
    int*      rowoff = (int*)bump((size_t)(NN + 8) * 4);
    uint_t*   epr    = (uint_t*)bump((size_t)NE * 4);
    uint_t*   ebin   = (uint_t*)bump((size_t)NE * 4);
    int*      histg  = (int*)bump((size_t)NCHK2 * NBIN2 * 4);  // 126 KB
    int*      Tb     = (int*)bump((size_t)(NBIN2 + 8) * 4);
    int*      boff   = (int*)bump((size_t)(NBIN2 + 8) * 4);
    ushort_t* aggs   = (ushort_t*)bump((size_t)NN * 128);
    ushort_t* xw2s   = (ushort_t*)bump((size_t)NN * 128);
    ushort_t* W2b    = (ushort_t*)bump((size_t)64 * 64 * 2);
    ushort_t* wpk    = (ushort_t*)bump((size_t)WPKN * 2);
    int*      bsum2  = (int*)bump((size_t)64 * 4);

    const int* src = ei;
    const int* dst = ei + NE;

    // zero: cnt2 + pool + seqb (contiguous by layout)
    int zn = NSEG + BATCH * 64 + BATCH * SEQROW * 64 + 16;
    k_zero<<<2048, 256, 0, stream>>>((float*)cnt2, zn);

    // seg histogram -> node sort
    k_seg<<<(NN + 255) / 256, 256, 0, stream>>>(batch, depth, segn, cnt2);
    k_scan_block<<<NBLK_S, 256, 0, stream>>>(cnt2, bsum2, NSEG);
    k_scan_top<<<1, 512, 0, stream>>>(bsum2, NBLK_S);
    k_scan_final<<<NBLK_S, 256, 0, stream>>>(cnt2, bsum2, soff, cursor2, NSEG, NN);
    k_nreorder<<<(NN + 255) / 256, 256, 0, stream>>>(segn, cursor2, nord, pos);

    // weight prep (independent)
    k_prepW<<<(WPKN + 255) / 256, 256, 0, stream>>>(W2, W2b, cw, wpk);

    // binned edge sort: hist -> totals -> offsets -> bases -> bin streams -> local sort
    k_binh2<<<NCHK2, 256, 0, stream>>>(dst, pos, histg);
    k_binT<<<NBIN2, 64, 0, stream>>>(histg, Tb);
    k_boff<<<1, 128, 0, stream>>>(Tb, boff);
    k_binbase<<<NBIN2, 64, 0, stream>>>(histg, boff);
    k_scatA2<<<NCHK2, 256, 0, stream>>>(src, dst, pos, histg, ebin);
    k_binsort<<<NBIN2, 256, 0, stream>>>(ebin, boff, epr, rowoff, dinvs);

    // xs after dinvs
    k_prepx<<<(NN + 255) / 256, 256, 0, stream>>>(x, nord, dinvs, xs);

    // fused layer-1 + layer-2 GEMM (writes xw2s directly)
    k_build12<<<4096, 256, 0, stream>>>(xs, W1, b1, dinvs, rowoff, epr, W2b, xw2s);

    // layer-2 aggregate (flat edge loop, pure adds, LDS accumulators)
    k_agg3<<<4096, 256, 0, stream>>>(xw2s, b2, dinvs, rowoff, epr, aggs);

    // pool (sequential over seg-sorted rows) -> bf16 padded seq
    k_pool2<<<NSEG / 4, 256, 0, stream>>>(aggs, soff, seqb);

    // conv + bias + relu + L-sum via MFMA
    k_convm<<<256, 256, 0, stream>>>(seqb, wpk, cb, pool);

    // head
    k_head<<<BATCH, 64, 0, stream>>>(pool, f1w, f1b, f2w, f2b, out);
}